// Round 7
// baseline (957.117 us; speedup 1.0000x reference)
//
#include <hip/hip_runtime.h>
#include <hip/hip_bf16.h>

#define NN 100000
#define NE 1600000
#define HID 64
#define SCAN_BS 256
#define NBLK ((NN + SCAN_BS - 1) / SCAN_BS)   // 391

__device__ __forceinline__ float bflo(unsigned u) { return __uint_as_float(u << 16); }
__device__ __forceinline__ float bfhi(unsigned u) { return __uint_as_float(u & 0xffff0000u); }
__device__ __forceinline__ unsigned short f2bf(float f) {
    __hip_bfloat16 h = (__hip_bfloat16)f;
    return *(unsigned short*)&h;
}

// ---------- CSR build ----------
__global__ void count_kernel(const int* __restrict__ dst, int* __restrict__ degI, int nE) {
    int e = blockIdx.x * blockDim.x + threadIdx.x;
    if (e < nE) atomicAdd(&degI[dst[e]], 1);
}

__global__ void scan1_kernel(const int* __restrict__ degI, int* __restrict__ rowtmp,
                             int* __restrict__ blockSum) {
    __shared__ int tmp[SCAN_BS];
    int t = threadIdx.x;
    int i = blockIdx.x * SCAN_BS + t;
    int d = (i < NN) ? degI[i] : 0;
    tmp[t] = d;
    __syncthreads();
    for (int off = 1; off < SCAN_BS; off <<= 1) {
        int v = (t >= off) ? tmp[t - off] : 0;
        __syncthreads();
        tmp[t] += v;
        __syncthreads();
    }
    if (i < NN) rowtmp[i] = tmp[t] - d;
    if (t == SCAN_BS - 1) blockSum[blockIdx.x] = tmp[t];
}

__global__ void scan2_kernel(const int* __restrict__ blockSum, int* __restrict__ blockOff, int n) {
    __shared__ int tmp[512];
    int t = threadIdx.x;
    tmp[t] = (t < n) ? blockSum[t] : 0;
    __syncthreads();
    for (int off = 1; off < 512; off <<= 1) {
        int v = (t >= off) ? tmp[t - off] : 0;
        __syncthreads();
        tmp[t] += v;
        __syncthreads();
    }
    if (t < n) blockOff[t] = (t == 0) ? 0 : tmp[t - 1];
}

__global__ void scan3_kernel(const int* __restrict__ rowtmp, const int* __restrict__ blockOff,
                             int* __restrict__ row_ptr) {
    int i = blockIdx.x * SCAN_BS + threadIdx.x;
    if (i < NN) row_ptr[i] = rowtmp[i] + blockOff[blockIdx.x];
}

__global__ void fill_kernel(const int* __restrict__ src, const int* __restrict__ dst,
                            const int* __restrict__ row_ptr, int* __restrict__ cursor,
                            int* __restrict__ csr_src, int nE) {
    int e = blockIdx.x * blockDim.x + threadIdx.x;
    if (e >= nE) return;
    int d = dst[e];
    int pos = atomicAdd(&cursor[d], 1);
    csr_src[row_ptr[d] + pos] = src[e];
}

// ---------- fused SAGE layer: R2 shape (wave-per-node, fp32, dword/lane, 4-deep),
// no __syncthreads (all LDS traffic is same-wave), LAST fuses a1/a2 projection ----------
template <int IN, bool RELU, bool LAST>
__launch_bounds__(256)
__global__ void sage_layer(const int* __restrict__ row_ptr, const int* __restrict__ degI,
                           const int* __restrict__ csr_src,
                           const float* __restrict__ hin,
                           const float* __restrict__ Wl, const float* __restrict__ bl,
                           const float* __restrict__ Wr,
                           float* __restrict__ hout,
                           const float* __restrict__ W1,
                           unsigned short* __restrict__ a1, unsigned short* __restrict__ a2) {
    constexpr int SPLIT = 64 / IN;                // edge slots per load instr (1 or 2)
    int g = threadIdx.x >> 6;
    int lane = threadIdx.x & 63;
    int node = blockIdx.x * 4 + g;                // grid NN/4 exact
    int f = lane & (IN - 1);
    int sub = lane / IN;

    __shared__ float part[4][64];
    __shared__ float sh[4][IN];
    __shared__ float sh2[4][64];                  // LAST only

    int start = row_ptr[node];
    int dg = degI[node];
    const int* cs = csr_src + start;

    float acc = 0.f;
    int e = sub;
    for (; e + 3 * SPLIT < dg; e += 4 * SPLIT) {
        int s0 = cs[e], s1 = cs[e + SPLIT], s2 = cs[e + 2 * SPLIT], s3 = cs[e + 3 * SPLIT];
        float v0 = hin[(size_t)s0 * IN + f];
        float v1 = hin[(size_t)s1 * IN + f];
        float v2 = hin[(size_t)s2 * IN + f];
        float v3 = hin[(size_t)s3 * IN + f];
        acc += (v0 + v1) + (v2 + v3);
    }
    for (; e < dg; e += SPLIT) acc += hin[(size_t)cs[e] * IN + f];
    if (sub == 0) sh[g][f] = hin[(size_t)node * IN + f];
    part[g][lane] = acc;                          // same-wave LDS: no barrier needed

    int j = lane;
    float oL = 0.f, oR = 0.f;
#pragma unroll
    for (int k = 0; k < IN; ++k) {
        float m = part[g][k];
        if (SPLIT == 2) m += part[g][32 + k];
        oL = fmaf(m, Wl[k * 64 + j], oL);
        oR = fmaf(sh[g][k], Wr[k * 64 + j], oR);
    }
    float rdeg = 1.0f / fmaxf((float)dg, 1.0f);
    float o = bl[j] + oL * rdeg + oR;
    if (RELU) o = fmaxf(o, 0.f);

    if (!LAST) {
        hout[(size_t)node * 64 + j] = o;
    } else {
        sh2[g][j] = o;                            // same-wave LDS: no barrier needed
        float A1 = 0.f, A2 = 0.f;
#pragma unroll
        for (int k = 0; k < 64; ++k) {
            float hv = sh2[g][k];
            A1 = fmaf(hv, W1[k * 64 + j], A1);
            A2 = fmaf(hv, W1[(64 + k) * 64 + j], A2);
        }
        a1[(size_t)node * 64 + j] = f2bf(A1);
        a2[(size_t)node * 64 + j] = f2bf(A2);
    }
}

// ---------- edge predictor ----------
__launch_bounds__(256)
__global__ void edge_pred(const int* __restrict__ src, const int* __restrict__ dst,
                          const unsigned short* __restrict__ a1, const unsigned short* __restrict__ a2,
                          const float* __restrict__ ea,
                          const float* __restrict__ W1, const float* __restrict__ b1,
                          const float* __restrict__ W2, const float* __restrict__ b2,
                          const float* __restrict__ W3, const float* __restrict__ b3,
                          float* __restrict__ out, int nE) {
    int e = blockIdx.x * blockDim.x + threadIdx.x;
    if (e >= nE) return;
    int s = src[e];
    int d = dst[e];

    const uint4* pa = (const uint4*)(a1 + (size_t)s * 64);
    const uint4* pb = (const uint4*)(a2 + (size_t)d * 64);
    const float4* eav = (const float4*)(ea + (size_t)e * 8);
    float4 v0 = eav[0];
    float4 v1 = eav[1];

    float z1[64];
    const float* wr = W1 + 128 * 64;
#pragma unroll
    for (int j = 0; j < 64; ++j) {
        float a = fmaf(v0.x, wr[j], b1[j]);
        a = fmaf(v0.y, wr[64 + j], a);
        a = fmaf(v0.z, wr[128 + j], a);
        a = fmaf(v0.w, wr[192 + j], a);
        a = fmaf(v1.x, wr[256 + j], a);
        a = fmaf(v1.y, wr[320 + j], a);
        a = fmaf(v1.z, wr[384 + j], a);
        z1[j] = fmaf(v1.w, wr[448 + j], a);
    }

#pragma unroll
    for (int q = 0; q < 8; ++q) {
        uint4 ua = pa[q];
        uint4 ub = pb[q];
        int j0 = q * 8;
        z1[j0 + 0] += bflo(ua.x) + bflo(ub.x);
        z1[j0 + 1] += bfhi(ua.x) + bfhi(ub.x);
        z1[j0 + 2] += bflo(ua.y) + bflo(ub.y);
        z1[j0 + 3] += bfhi(ua.y) + bfhi(ub.y);
        z1[j0 + 4] += bflo(ua.z) + bflo(ub.z);
        z1[j0 + 5] += bfhi(ua.z) + bfhi(ub.z);
        z1[j0 + 6] += bflo(ua.w) + bflo(ub.w);
        z1[j0 + 7] += bfhi(ua.w) + bfhi(ub.w);
    }

    float z2[32];
#pragma unroll
    for (int j = 0; j < 32; ++j) z2[j] = b2[j];
    for (int k = 0; k < 64; ++k) {
        float v = fmaxf(z1[k], 0.0f);
        const float* w = W2 + (size_t)k * 32;
#pragma unroll
        for (int j = 0; j < 32; ++j) z2[j] = fmaf(v, w[j], z2[j]);
    }

    float o = b3[0];
#pragma unroll
    for (int k = 0; k < 32; ++k) o = fmaf(fmaxf(z2[k], 0.0f), W3[k], o);

    out[e] = 1.0f / (1.0f + __expf(-o));
}

extern "C" void kernel_launch(void* const* d_in, const int* in_sizes, int n_in,
                              void* d_out, int out_size, void* d_ws, size_t ws_size,
                              hipStream_t stream) {
    const float* x   = (const float*)d_in[0];
    const int*   ei  = (const int*)d_in[1];
    const float* ea  = (const float*)d_in[2];
    const float* Wl0 = (const float*)d_in[3];
    const float* bl0 = (const float*)d_in[4];
    const float* Wr0 = (const float*)d_in[5];
    const float* Wl1 = (const float*)d_in[6];
    const float* bl1 = (const float*)d_in[7];
    const float* Wr1 = (const float*)d_in[8];
    const float* Wl2 = (const float*)d_in[9];
    const float* bl2 = (const float*)d_in[10];
    const float* Wr2 = (const float*)d_in[11];
    const float* W1  = (const float*)d_in[12];
    const float* b1  = (const float*)d_in[13];
    const float* W2  = (const float*)d_in[14];
    const float* b2  = (const float*)d_in[15];
    const float* W3  = (const float*)d_in[16];
    const float* b3  = (const float*)d_in[17];

    const int* src = ei;
    const int* dst = ei + NE;

    char* ws = (char*)d_ws;
    size_t off = 0;
    auto alloc = [&](size_t bytes) {
        void* p = ws + off;
        off += (bytes + 255) & ~(size_t)255;
        return p;
    };
    float* hA = (float*)alloc((size_t)NN * HID * sizeof(float));
    float* hB = (float*)alloc((size_t)NN * HID * sizeof(float));
    unsigned short* a1 = (unsigned short*)alloc((size_t)NN * HID * 2);
    unsigned short* a2 = (unsigned short*)alloc((size_t)NN * HID * 2);
    int* degI    = (int*)alloc(NN * sizeof(int));
    int* row_ptr = (int*)alloc(NN * sizeof(int));
    int* rowtmp  = (int*)alloc(NN * sizeof(int));
    int* cursor  = (int*)alloc(NN * sizeof(int));
    int* blockSum= (int*)alloc(512 * sizeof(int));
    int* blockOff= (int*)alloc(512 * sizeof(int));
    int* csr_src = (int*)alloc((size_t)NE * sizeof(int));
    float* out = (float*)d_out;

    const int BS = 256;
    dim3 blkE((NE + BS - 1) / BS);
    dim3 blkN4(NN / 4);                 // wave-per-node, 4 nodes/block, NN % 4 == 0

    // ---- CSR build ----
    hipMemsetAsync(degI, 0, NN * sizeof(int), stream);
    hipMemsetAsync(cursor, 0, NN * sizeof(int), stream);
    count_kernel<<<blkE, BS, 0, stream>>>(dst, degI, NE);
    scan1_kernel<<<NBLK, SCAN_BS, 0, stream>>>(degI, rowtmp, blockSum);
    scan2_kernel<<<1, 512, 0, stream>>>(blockSum, blockOff, NBLK);
    scan3_kernel<<<NBLK, SCAN_BS, 0, stream>>>(rowtmp, blockOff, row_ptr);
    fill_kernel<<<blkE, BS, 0, stream>>>(src, dst, row_ptr, cursor, csr_src, NE);

    // ---- 3 SAGE layers (R2 shape; last fuses bf16 a1/a2 projection) ----
    sage_layer<32, true,  false><<<blkN4, 256, 0, stream>>>(row_ptr, degI, csr_src, x,  Wl0, bl0, Wr0, hA, nullptr, nullptr, nullptr);
    sage_layer<64, true,  false><<<blkN4, 256, 0, stream>>>(row_ptr, degI, csr_src, hA, Wl1, bl1, Wr1, hB, nullptr, nullptr, nullptr);
    sage_layer<64, false, true ><<<blkN4, 256, 0, stream>>>(row_ptr, degI, csr_src, hB, Wl2, bl2, Wr2, nullptr, W1, a1, a2);

    // ---- edge predictor ----
    edge_pred<<<blkE, BS, 0, stream>>>(src, dst, a1, a2, ea, W1, b1, W2, b2, W3, b3, out, NE);
}

// Round 8
// 827.700 us; speedup vs baseline: 1.1564x; 1.1564x over previous
//
#include <hip/hip_runtime.h>
#include <hip/hip_bf16.h>

#define NN 100000
#define NE 1600000
#define HID 64
#define SCAN_BS 256
#define NBLK ((NN + SCAN_BS - 1) / SCAN_BS)   // 391

__device__ __forceinline__ float bflo(unsigned u) { return __uint_as_float(u << 16); }
__device__ __forceinline__ float bfhi(unsigned u) { return __uint_as_float(u & 0xffff0000u); }
__device__ __forceinline__ unsigned short f2bf(float f) {
    __hip_bfloat16 h = (__hip_bfloat16)f;
    return *(unsigned short*)&h;
}

// ---------- CSR build ----------
__global__ void count_kernel(const int* __restrict__ dst, int* __restrict__ degI, int nE) {
    int e = blockIdx.x * blockDim.x + threadIdx.x;
    if (e < nE) atomicAdd(&degI[dst[e]], 1);
}

__global__ void scan1_kernel(const int* __restrict__ degI, int* __restrict__ rowtmp,
                             int* __restrict__ blockSum) {
    __shared__ int tmp[SCAN_BS];
    int t = threadIdx.x;
    int i = blockIdx.x * SCAN_BS + t;
    int d = (i < NN) ? degI[i] : 0;
    tmp[t] = d;
    __syncthreads();
    for (int off = 1; off < SCAN_BS; off <<= 1) {
        int v = (t >= off) ? tmp[t - off] : 0;
        __syncthreads();
        tmp[t] += v;
        __syncthreads();
    }
    if (i < NN) rowtmp[i] = tmp[t] - d;           // exclusive within block
    if (t == SCAN_BS - 1) blockSum[blockIdx.x] = tmp[t];
}

__global__ void scan2_kernel(const int* __restrict__ blockSum, int* __restrict__ blockOff, int n) {
    __shared__ int tmp[512];
    int t = threadIdx.x;
    tmp[t] = (t < n) ? blockSum[t] : 0;
    __syncthreads();
    for (int off = 1; off < 512; off <<= 1) {
        int v = (t >= off) ? tmp[t - off] : 0;
        __syncthreads();
        tmp[t] += v;
        __syncthreads();
    }
    if (t < n) blockOff[t] = (t == 0) ? 0 : tmp[t - 1];
}

__global__ void scan3_kernel(const int* __restrict__ rowtmp, const int* __restrict__ blockOff,
                             int* __restrict__ row_ptr) {
    int i = blockIdx.x * SCAN_BS + threadIdx.x;
    if (i < NN) row_ptr[i] = rowtmp[i] + blockOff[blockIdx.x];
}

__global__ void fill_kernel(const int* __restrict__ src, const int* __restrict__ dst,
                            const int* __restrict__ row_ptr, int* __restrict__ cursor,
                            int* __restrict__ csr_src, int nE) {
    int e = blockIdx.x * blockDim.x + threadIdx.x;
    if (e >= nE) return;
    int d = dst[e];
    int pos = atomicAdd(&cursor[d], 1);
    csr_src[row_ptr[d] + pos] = src[e];
}

// ---------- fused SAGE layer: R2-exact shape (wave-per-node, fp32 dword/lane,
// 4-deep unroll, __syncthreads kept as register-pressure fence).
// LAST additionally projects hout into bf16 a1/a2 (R3-validated fusion). ----------
template <int IN, bool RELU, bool LAST>
__launch_bounds__(256)
__global__ void sage_layer(const int* __restrict__ row_ptr, const int* __restrict__ degI,
                           const int* __restrict__ csr_src,
                           const float* __restrict__ hin,
                           const float* __restrict__ Wl, const float* __restrict__ bl,
                           const float* __restrict__ Wr,
                           float* __restrict__ hout,
                           const float* __restrict__ W1,
                           unsigned short* __restrict__ a1, unsigned short* __restrict__ a2) {
    constexpr int SPLIT = 64 / IN;                // 2 for IN=32, 1 for IN=64
    int g = threadIdx.x >> 6;                     // node group within block (0..3)
    int lane = threadIdx.x & 63;
    int node = blockIdx.x * 4 + g;
    bool valid = node < NN;
    int f = lane & (IN - 1);
    int half = lane / IN;

    __shared__ float part[4][64];
    __shared__ float sh[4][IN];
    __shared__ float sh2[4][64];                  // LAST only

    float acc = 0.f;
    int dg = 0;
    if (valid) {
        int start = row_ptr[node];
        dg = degI[node];
        const int* cs = csr_src + start;
        int e = half;
        for (; e + 3 * SPLIT < dg; e += 4 * SPLIT) {
            int s0 = cs[e], s1 = cs[e + SPLIT], s2 = cs[e + 2 * SPLIT], s3 = cs[e + 3 * SPLIT];
            float v0 = hin[(size_t)s0 * IN + f];
            float v1 = hin[(size_t)s1 * IN + f];
            float v2 = hin[(size_t)s2 * IN + f];
            float v3 = hin[(size_t)s3 * IN + f];
            acc += (v0 + v1) + (v2 + v3);
        }
        for (; e < dg; e += SPLIT) acc += hin[(size_t)cs[e] * IN + f];
        if (half == 0) sh[g][f] = hin[(size_t)node * IN + f];
    }
    part[g][lane] = acc;
    __syncthreads();

    float o = 0.f;
    int j = lane;
    if (valid) {
        float rdeg = 1.0f / fmaxf((float)dg, 1.0f);
        float oL = 0.f, oR = 0.f;
#pragma unroll
        for (int k = 0; k < IN; ++k) {
            float m = part[g][k];
            if (SPLIT == 2) m += part[g][k + 32];
            oL = fmaf(m, Wl[k * 64 + j], oL);
            oR = fmaf(sh[g][k], Wr[k * 64 + j], oR);
        }
        o = bl[j] + oL * rdeg + oR;
        if (RELU) o = fmaxf(o, 0.f);
        if (!LAST) hout[(size_t)node * 64 + j] = o;
    }

    if (LAST) {
        if (valid) sh2[g][j] = o;
        __syncthreads();
        if (valid) {
            float A1 = 0.f, A2 = 0.f;
#pragma unroll
            for (int k = 0; k < 64; ++k) {
                float hv = sh2[g][k];
                A1 = fmaf(hv, W1[k * 64 + j], A1);
                A2 = fmaf(hv, W1[(64 + k) * 64 + j], A2);
            }
            a1[(size_t)node * 64 + j] = f2bf(A1);
            a2[(size_t)node * 64 + j] = f2bf(A2);
        }
    }
}

// ---------- edge predictor ----------
__launch_bounds__(256)
__global__ void edge_pred(const int* __restrict__ src, const int* __restrict__ dst,
                          const unsigned short* __restrict__ a1, const unsigned short* __restrict__ a2,
                          const float* __restrict__ ea,
                          const float* __restrict__ W1, const float* __restrict__ b1,
                          const float* __restrict__ W2, const float* __restrict__ b2,
                          const float* __restrict__ W3, const float* __restrict__ b3,
                          float* __restrict__ out, int nE) {
    int e = blockIdx.x * blockDim.x + threadIdx.x;
    if (e >= nE) return;
    int s = src[e];
    int d = dst[e];

    const uint4* pa = (const uint4*)(a1 + (size_t)s * 64);
    const uint4* pb = (const uint4*)(a2 + (size_t)d * 64);
    const float4* eav = (const float4*)(ea + (size_t)e * 8);
    float4 v0 = eav[0];
    float4 v1 = eav[1];

    float z1[64];
    const float* wr = W1 + 128 * 64;
#pragma unroll
    for (int j = 0; j < 64; ++j) {
        float a = fmaf(v0.x, wr[j], b1[j]);
        a = fmaf(v0.y, wr[64 + j], a);
        a = fmaf(v0.z, wr[128 + j], a);
        a = fmaf(v0.w, wr[192 + j], a);
        a = fmaf(v1.x, wr[256 + j], a);
        a = fmaf(v1.y, wr[320 + j], a);
        a = fmaf(v1.z, wr[384 + j], a);
        z1[j] = fmaf(v1.w, wr[448 + j], a);
    }

#pragma unroll
    for (int q = 0; q < 8; ++q) {
        uint4 ua = pa[q];
        uint4 ub = pb[q];
        int j0 = q * 8;
        z1[j0 + 0] += bflo(ua.x) + bflo(ub.x);
        z1[j0 + 1] += bfhi(ua.x) + bfhi(ub.x);
        z1[j0 + 2] += bflo(ua.y) + bflo(ub.y);
        z1[j0 + 3] += bfhi(ua.y) + bfhi(ub.y);
        z1[j0 + 4] += bflo(ua.z) + bflo(ub.z);
        z1[j0 + 5] += bfhi(ua.z) + bfhi(ub.z);
        z1[j0 + 6] += bflo(ua.w) + bflo(ub.w);
        z1[j0 + 7] += bfhi(ua.w) + bfhi(ub.w);
    }

    float z2[32];
#pragma unroll
    for (int j = 0; j < 32; ++j) z2[j] = b2[j];
    for (int k = 0; k < 64; ++k) {
        float v = fmaxf(z1[k], 0.0f);
        const float* w = W2 + (size_t)k * 32;
#pragma unroll
        for (int j = 0; j < 32; ++j) z2[j] = fmaf(v, w[j], z2[j]);
    }

    float o = b3[0];
#pragma unroll
    for (int k = 0; k < 32; ++k) o = fmaf(fmaxf(z2[k], 0.0f), W3[k], o);

    out[e] = 1.0f / (1.0f + __expf(-o));
}

extern "C" void kernel_launch(void* const* d_in, const int* in_sizes, int n_in,
                              void* d_out, int out_size, void* d_ws, size_t ws_size,
                              hipStream_t stream) {
    const float* x   = (const float*)d_in[0];
    const int*   ei  = (const int*)d_in[1];
    const float* ea  = (const float*)d_in[2];
    const float* Wl0 = (const float*)d_in[3];
    const float* bl0 = (const float*)d_in[4];
    const float* Wr0 = (const float*)d_in[5];
    const float* Wl1 = (const float*)d_in[6];
    const float* bl1 = (const float*)d_in[7];
    const float* Wr1 = (const float*)d_in[8];
    const float* Wl2 = (const float*)d_in[9];
    const float* bl2 = (const float*)d_in[10];
    const float* Wr2 = (const float*)d_in[11];
    const float* W1  = (const float*)d_in[12];
    const float* b1  = (const float*)d_in[13];
    const float* W2  = (const float*)d_in[14];
    const float* b2  = (const float*)d_in[15];
    const float* W3  = (const float*)d_in[16];
    const float* b3  = (const float*)d_in[17];

    const int* src = ei;
    const int* dst = ei + NE;

    char* ws = (char*)d_ws;
    size_t off = 0;
    auto alloc = [&](size_t bytes) {
        void* p = ws + off;
        off += (bytes + 255) & ~(size_t)255;
        return p;
    };
    float* hA = (float*)alloc((size_t)NN * HID * sizeof(float));
    float* hB = (float*)alloc((size_t)NN * HID * sizeof(float));
    unsigned short* a1 = (unsigned short*)alloc((size_t)NN * HID * 2);
    unsigned short* a2 = (unsigned short*)alloc((size_t)NN * HID * 2);
    int* degI    = (int*)alloc(NN * sizeof(int));
    int* row_ptr = (int*)alloc(NN * sizeof(int));
    int* rowtmp  = (int*)alloc(NN * sizeof(int));
    int* cursor  = (int*)alloc(NN * sizeof(int));
    int* blockSum= (int*)alloc(512 * sizeof(int));
    int* blockOff= (int*)alloc(512 * sizeof(int));
    int* csr_src = (int*)alloc((size_t)NE * sizeof(int));
    float* out = (float*)d_out;

    const int BS = 256;
    dim3 blkE((NE + BS - 1) / BS);
    dim3 blkN4((NN + 3) / 4);

    // ---- CSR build ----
    hipMemsetAsync(degI, 0, NN * sizeof(int), stream);
    hipMemsetAsync(cursor, 0, NN * sizeof(int), stream);
    count_kernel<<<blkE, BS, 0, stream>>>(dst, degI, NE);
    scan1_kernel<<<NBLK, SCAN_BS, 0, stream>>>(degI, rowtmp, blockSum);
    scan2_kernel<<<1, 512, 0, stream>>>(blockSum, blockOff, NBLK);
    scan3_kernel<<<NBLK, SCAN_BS, 0, stream>>>(rowtmp, blockOff, row_ptr);
    fill_kernel<<<blkE, BS, 0, stream>>>(src, dst, row_ptr, cursor, csr_src, NE);

    // ---- 3 SAGE layers (R2-exact; last fuses bf16 a1/a2 projection) ----
    sage_layer<32, true,  false><<<blkN4, 256, 0, stream>>>(row_ptr, degI, csr_src, x,  Wl0, bl0, Wr0, hA, nullptr, nullptr, nullptr);
    sage_layer<64, true,  false><<<blkN4, 256, 0, stream>>>(row_ptr, degI, csr_src, hA, Wl1, bl1, Wr1, hB, nullptr, nullptr, nullptr);
    sage_layer<64, false, true ><<<blkN4, 256, 0, stream>>>(row_ptr, degI, csr_src, hB, Wl2, bl2, Wr2, nullptr, W1, a1, a2);

    // ---- edge predictor ----
    edge_pred<<<blkE, BS, 0, stream>>>(src, dst, a1, a2, ea, W1, b1, W2, b2, W3, b3, out, NE);
}